// Round 1
// baseline (2934.952 us; speedup 1.0000x reference)
//
#include <hip/hip_runtime.h>

// MPNN: h1 = relu(segsum(feat[src] -> dst) @ W1^T + b1)
//       out = segsum(h1[src] -> dst) @ W2^T + b2
// N=50000 nodes, E=800000 edges, d=128 throughout. All f32.
//
// d_in order: features[N*128], src[E], dst[E], W1[128*128], b1[128], W2[128*128], b2[128]
// ws layout: [0, N*128) floats = h_neigh accumulator
//            [N*128, +16384)   = WT1 (transposed W1, [in][out])
//            [.., +16384)      = WT2

#define NDIM 128

__global__ void transpose_w2(const float* __restrict__ W1, const float* __restrict__ W2,
                             float* __restrict__ WT1, float* __restrict__ WT2) {
    int tid = blockIdx.x * 256 + threadIdx.x;   // 32768 threads total
    int which = tid >> 14;                      // 16384 per matrix
    int t = tid & 16383;
    int o = t >> 7;          // out index (row of W)
    int i = t & 127;         // in index  (col of W)
    if (which == 0) WT1[i * NDIM + o] = W1[o * NDIM + i];
    else            WT2[i * NDIM + o] = W2[o * NDIM + i];
}

// One edge handled by 32 consecutive threads; each thread does a float4 gather
// + 4 scalar atomic adds into the destination row.
__global__ void scatter_add(const float* __restrict__ feat,
                            const int* __restrict__ src,
                            const int* __restrict__ dst,
                            float* __restrict__ out, int n_edges) {
    long tid = (long)blockIdx.x * blockDim.x + threadIdx.x;
    long total = (long)n_edges * 32;
    if (tid >= total) return;
    int e  = (int)(tid >> 5);
    int j4 = (int)(tid & 31) << 2;
    int s = src[e];
    int d = dst[e];
    float4 v = *reinterpret_cast<const float4*>(feat + (size_t)s * NDIM + j4);
    float* o = out + (size_t)d * NDIM + j4;
    atomicAdd(o + 0, v.x);
    atomicAdd(o + 1, v.y);
    atomicAdd(o + 2, v.z);
    atomicAdd(o + 3, v.w);
}

// out[row][c4..c4+3] = h[row][:] dot WT[:, c4..c4+3] (+bias, opt relu)
// 32 threads per row, 4 output cols per thread. WT reads are coalesced and
// L1/L2-resident (64KB); h reads are wave-broadcast float4s.
template <bool RELU>
__global__ void linear_k(const float* __restrict__ h, const float* __restrict__ WT,
                         const float* __restrict__ bias, float* __restrict__ out,
                         int n_nodes) {
    int tid = blockIdx.x * blockDim.x + threadIdx.x;
    int row = tid >> 5;
    if (row >= n_nodes) return;
    int c4 = (tid & 31) << 2;
    const float4* h4 = reinterpret_cast<const float4*>(h + (size_t)row * NDIM);
    float4 acc = make_float4(0.f, 0.f, 0.f, 0.f);
#pragma unroll 8
    for (int k4 = 0; k4 < 32; ++k4) {
        float4 hv = h4[k4];
        const float* wt = WT + (k4 * 4) * NDIM + c4;
        float4 w0 = *reinterpret_cast<const float4*>(wt);
        float4 w1 = *reinterpret_cast<const float4*>(wt + NDIM);
        float4 w2 = *reinterpret_cast<const float4*>(wt + 2 * NDIM);
        float4 w3 = *reinterpret_cast<const float4*>(wt + 3 * NDIM);
        acc.x = fmaf(hv.x, w0.x, acc.x); acc.y = fmaf(hv.x, w0.y, acc.y);
        acc.z = fmaf(hv.x, w0.z, acc.z); acc.w = fmaf(hv.x, w0.w, acc.w);
        acc.x = fmaf(hv.y, w1.x, acc.x); acc.y = fmaf(hv.y, w1.y, acc.y);
        acc.z = fmaf(hv.y, w1.z, acc.z); acc.w = fmaf(hv.y, w1.w, acc.w);
        acc.x = fmaf(hv.z, w2.x, acc.x); acc.y = fmaf(hv.z, w2.y, acc.y);
        acc.z = fmaf(hv.z, w2.z, acc.z); acc.w = fmaf(hv.z, w2.w, acc.w);
        acc.x = fmaf(hv.w, w3.x, acc.x); acc.y = fmaf(hv.w, w3.y, acc.y);
        acc.z = fmaf(hv.w, w3.z, acc.z); acc.w = fmaf(hv.w, w3.w, acc.w);
    }
    float4 bv = *reinterpret_cast<const float4*>(bias + c4);
    acc.x += bv.x; acc.y += bv.y; acc.z += bv.z; acc.w += bv.w;
    if (RELU) {
        acc.x = fmaxf(acc.x, 0.f); acc.y = fmaxf(acc.y, 0.f);
        acc.z = fmaxf(acc.z, 0.f); acc.w = fmaxf(acc.w, 0.f);
    }
    *reinterpret_cast<float4*>(out + (size_t)row * NDIM + c4) = acc;
}

extern "C" void kernel_launch(void* const* d_in, const int* in_sizes, int n_in,
                              void* d_out, int out_size, void* d_ws, size_t ws_size,
                              hipStream_t stream) {
    const float* features = (const float*)d_in[0];
    const int*   src      = (const int*)d_in[1];
    const int*   dst      = (const int*)d_in[2];
    const float* W1       = (const float*)d_in[3];
    const float* b1       = (const float*)d_in[4];
    const float* W2       = (const float*)d_in[5];
    const float* b2       = (const float*)d_in[6];
    float* out = (float*)d_out;

    int n_nodes = in_sizes[0] / NDIM;   // 50000
    int n_edges = in_sizes[1];          // 800000

    float* hneigh = (float*)d_ws;                         // N*128 floats
    float* WT1 = hneigh + (size_t)n_nodes * NDIM;         // 16384 floats
    float* WT2 = WT1 + NDIM * NDIM;

    // Transpose both weight matrices
    transpose_w2<<<128, 256, 0, stream>>>(W1, W2, WT1, WT2);

    // ---- Layer 1 ----
    hipMemsetAsync(hneigh, 0, (size_t)n_nodes * NDIM * sizeof(float), stream);
    {
        long total = (long)n_edges * 32;
        int blocks = (int)((total + 255) / 256);
        scatter_add<<<blocks, 256, 0, stream>>>(features, src, dst, hneigh, n_edges);
    }
    {
        int total = n_nodes * 32;
        int blocks = (total + 255) / 256;
        linear_k<true><<<blocks, 256, 0, stream>>>(hneigh, WT1, b1, out, n_nodes);
    }

    // ---- Layer 2 ---- (h1 lives in d_out; gather from it, then overwrite)
    hipMemsetAsync(hneigh, 0, (size_t)n_nodes * NDIM * sizeof(float), stream);
    {
        long total = (long)n_edges * 32;
        int blocks = (int)((total + 255) / 256);
        scatter_add<<<blocks, 256, 0, stream>>>(out, src, dst, hneigh, n_edges);
    }
    {
        int total = n_nodes * 32;
        int blocks = (total + 255) / 256;
        linear_k<false><<<blocks, 256, 0, stream>>>(hneigh, WT2, b2, out, n_nodes);
    }
}

// Round 2
// 555.094 us; speedup vs baseline: 5.2873x; 5.2873x over previous
//
#include <hip/hip_runtime.h>

// MPNN: h1 = relu(segsum(feat[src] -> dst) @ W1^T + b1)
//       out = segsum(h1[src] -> dst) @ W2^T + b2
// N=50000 nodes, E=800000 edges, d=128, all f32.
//
// Strategy: build CSR by dst once per launch (int atomics only), then
// gather-side reduction (1 wave per dst node, float2/lane accumulator in
// registers) -> no f32 atomics, write traffic 25.6MB instead of 1.6GB.

#define NDIM 128

// ---------------- weight transpose ----------------
__global__ void transpose_w2(const float* __restrict__ W1, const float* __restrict__ W2,
                             float* __restrict__ WT1, float* __restrict__ WT2) {
    int tid = blockIdx.x * 256 + threadIdx.x;   // 32768 threads total
    int which = tid >> 14;
    int t = tid & 16383;
    int o = t >> 7;
    int i = t & 127;
    if (which == 0) WT1[i * NDIM + o] = W1[o * NDIM + i];
    else            WT2[i * NDIM + o] = W2[o * NDIM + i];
}

// ---------------- CSR build ----------------
__global__ void hist_dst(const int* __restrict__ dst, int* __restrict__ counts, int n_edges) {
    int i = blockIdx.x * blockDim.x + threadIdx.x;
    if (i < n_edges) atomicAdd(&counts[dst[i]], 1);
}

// Single-block exclusive scan over counts[n] -> row_ptr[n+1], cursor[n].
__global__ __launch_bounds__(1024) void scan_counts(const int* __restrict__ counts,
                                                    int* __restrict__ row_ptr,
                                                    int* __restrict__ cursor, int n) {
    __shared__ int part[1024];
    int t = threadIdx.x;
    int chunk = (n + 1023) / 1024;
    int beg = t * chunk;
    int end = min(beg + chunk, n);
    int s = 0;
    for (int i = beg; i < end; ++i) s += counts[i];
    part[t] = s;
    __syncthreads();
    // Hillis-Steele inclusive scan
    for (int off = 1; off < 1024; off <<= 1) {
        int v = (t >= off) ? part[t - off] : 0;
        __syncthreads();
        part[t] += v;
        __syncthreads();
    }
    int run = (t == 0) ? 0 : part[t - 1];
    for (int i = beg; i < end; ++i) {
        row_ptr[i] = run;
        cursor[i]  = run;
        run += counts[i];
    }
    if (beg < n && end == n) row_ptr[n] = run;          // thread covering last elem
    if (t == 1023 && beg >= n) row_ptr[n] = (t == 0) ? 0 : part[t - 1];
}

__global__ void fill_csr(const int* __restrict__ src, const int* __restrict__ dst,
                         int* __restrict__ cursor, int* __restrict__ col, int n_edges) {
    int i = blockIdx.x * blockDim.x + threadIdx.x;
    if (i < n_edges) {
        int pos = atomicAdd(&cursor[dst[i]], 1);
        col[pos] = src[i];
    }
}

// ---------------- gather-side segment sum ----------------
// One 64-lane wave per dst node; lane holds float2 (cols 2*lane, 2*lane+1).
__global__ void aggregate(const float* __restrict__ feat,
                          const int* __restrict__ row_ptr,
                          const int* __restrict__ col,
                          float* __restrict__ out, int n_nodes) {
    int wid  = (blockIdx.x * blockDim.x + threadIdx.x) >> 6;
    int lane = threadIdx.x & 63;
    if (wid >= n_nodes) return;
    int beg = row_ptr[wid];
    int end = row_ptr[wid + 1];
    float accx = 0.f, accy = 0.f;
    int k = beg;
    if (k < end) {
        int s0 = col[k];
        for (; k + 1 < end; ++k) {
            int s1 = col[k + 1];                       // prefetch next index
            float2 v = *reinterpret_cast<const float2*>(feat + (size_t)s0 * NDIM + lane * 2);
            accx += v.x; accy += v.y;
            s0 = s1;
        }
        float2 v = *reinterpret_cast<const float2*>(feat + (size_t)s0 * NDIM + lane * 2);
        accx += v.x; accy += v.y;
    }
    float2 r; r.x = accx; r.y = accy;
    *reinterpret_cast<float2*>(out + (size_t)wid * NDIM + lane * 2) = r;
}

// ---------------- dense linear ----------------
// 32 threads per row, 4 output cols per thread; WT is [in][out].
template <bool RELU>
__global__ void linear_k(const float* __restrict__ h, const float* __restrict__ WT,
                         const float* __restrict__ bias, float* __restrict__ out,
                         int n_nodes) {
    int tid = blockIdx.x * blockDim.x + threadIdx.x;
    int row = tid >> 5;
    if (row >= n_nodes) return;
    int c4 = (tid & 31) << 2;
    const float4* h4 = reinterpret_cast<const float4*>(h + (size_t)row * NDIM);
    float4 acc = make_float4(0.f, 0.f, 0.f, 0.f);
#pragma unroll 8
    for (int k4 = 0; k4 < 32; ++k4) {
        float4 hv = h4[k4];
        const float* wt = WT + (k4 * 4) * NDIM + c4;
        float4 w0 = *reinterpret_cast<const float4*>(wt);
        float4 w1 = *reinterpret_cast<const float4*>(wt + NDIM);
        float4 w2 = *reinterpret_cast<const float4*>(wt + 2 * NDIM);
        float4 w3 = *reinterpret_cast<const float4*>(wt + 3 * NDIM);
        acc.x = fmaf(hv.x, w0.x, acc.x); acc.y = fmaf(hv.x, w0.y, acc.y);
        acc.z = fmaf(hv.x, w0.z, acc.z); acc.w = fmaf(hv.x, w0.w, acc.w);
        acc.x = fmaf(hv.y, w1.x, acc.x); acc.y = fmaf(hv.y, w1.y, acc.y);
        acc.z = fmaf(hv.y, w1.z, acc.z); acc.w = fmaf(hv.y, w1.w, acc.w);
        acc.x = fmaf(hv.z, w2.x, acc.x); acc.y = fmaf(hv.z, w2.y, acc.y);
        acc.z = fmaf(hv.z, w2.z, acc.z); acc.w = fmaf(hv.z, w2.w, acc.w);
        acc.x = fmaf(hv.w, w3.x, acc.x); acc.y = fmaf(hv.w, w3.y, acc.y);
        acc.z = fmaf(hv.w, w3.z, acc.z); acc.w = fmaf(hv.w, w3.w, acc.w);
    }
    float4 bv = *reinterpret_cast<const float4*>(bias + c4);
    acc.x += bv.x; acc.y += bv.y; acc.z += bv.z; acc.w += bv.w;
    if (RELU) {
        acc.x = fmaxf(acc.x, 0.f); acc.y = fmaxf(acc.y, 0.f);
        acc.z = fmaxf(acc.z, 0.f); acc.w = fmaxf(acc.w, 0.f);
    }
    *reinterpret_cast<float4*>(out + (size_t)row * NDIM + c4) = acc;
}

// ---------------- fallback (atomic) path, used only if ws too small ----------
__global__ void scatter_add(const float* __restrict__ feat,
                            const int* __restrict__ src,
                            const int* __restrict__ dst,
                            float* __restrict__ out, int n_edges) {
    long tid = (long)blockIdx.x * blockDim.x + threadIdx.x;
    long total = (long)n_edges * 32;
    if (tid >= total) return;
    int e  = (int)(tid >> 5);
    int j4 = (int)(tid & 31) << 2;
    int s = src[e];
    int d = dst[e];
    float4 v = *reinterpret_cast<const float4*>(feat + (size_t)s * NDIM + j4);
    float* o = out + (size_t)d * NDIM + j4;
    atomicAdd(o + 0, v.x);
    atomicAdd(o + 1, v.y);
    atomicAdd(o + 2, v.z);
    atomicAdd(o + 3, v.w);
}

extern "C" void kernel_launch(void* const* d_in, const int* in_sizes, int n_in,
                              void* d_out, int out_size, void* d_ws, size_t ws_size,
                              hipStream_t stream) {
    const float* features = (const float*)d_in[0];
    const int*   src      = (const int*)d_in[1];
    const int*   dst      = (const int*)d_in[2];
    const float* W1       = (const float*)d_in[3];
    const float* b1       = (const float*)d_in[4];
    const float* W2       = (const float*)d_in[5];
    const float* b2       = (const float*)d_in[6];
    float* out = (float*)d_out;

    int n_nodes = in_sizes[0] / NDIM;   // 50000
    int n_edges = in_sizes[1];          // 800000

    // ws layout
    float* hneigh = (float*)d_ws;                          // N*128 floats
    float* WT1    = hneigh + (size_t)n_nodes * NDIM;       // 16384
    float* WT2    = WT1 + NDIM * NDIM;                     // 16384
    int*   counts  = (int*)(WT2 + NDIM * NDIM);            // N
    int*   row_ptr = counts + n_nodes;                     // N+1
    int*   cursor  = row_ptr + n_nodes + 1;                // N
    int*   col     = cursor + n_nodes;                     // E
    size_t needed = ((size_t)n_nodes * NDIM + 2 * NDIM * NDIM) * sizeof(float)
                  + ((size_t)3 * n_nodes + 1 + n_edges) * sizeof(int);

    transpose_w2<<<128, 256, 0, stream>>>(W1, W2, WT1, WT2);

    if (ws_size >= needed) {
        // ---- CSR build (once, reused by both layers) ----
        hipMemsetAsync(counts, 0, (size_t)n_nodes * sizeof(int), stream);
        int eb = (n_edges + 255) / 256;
        hist_dst<<<eb, 256, 0, stream>>>(dst, counts, n_edges);
        scan_counts<<<1, 1024, 0, stream>>>(counts, row_ptr, cursor, n_nodes);
        fill_csr<<<eb, 256, 0, stream>>>(src, dst, cursor, col, n_edges);

        int ab = (n_nodes * 64 + 255) / 256;  // one wave per node
        int lb = (n_nodes * 32 + 255) / 256;

        // ---- Layer 1 ----
        aggregate<<<ab, 256, 0, stream>>>(features, row_ptr, col, hneigh, n_nodes);
        linear_k<true><<<lb, 256, 0, stream>>>(hneigh, WT1, b1, out, n_nodes);
        // ---- Layer 2 ---- (h1 lives in d_out)
        aggregate<<<ab, 256, 0, stream>>>(out, row_ptr, col, hneigh, n_nodes);
        linear_k<false><<<lb, 256, 0, stream>>>(hneigh, WT2, b2, out, n_nodes);
    } else {
        // ---- fallback: atomic scatter path ----
        long total = (long)n_edges * 32;
        int sb = (int)((total + 255) / 256);
        int lb = (n_nodes * 32 + 255) / 256;

        hipMemsetAsync(hneigh, 0, (size_t)n_nodes * NDIM * sizeof(float), stream);
        scatter_add<<<sb, 256, 0, stream>>>(features, src, dst, hneigh, n_edges);
        linear_k<true><<<lb, 256, 0, stream>>>(hneigh, WT1, b1, out, n_nodes);
        hipMemsetAsync(hneigh, 0, (size_t)n_nodes * NDIM * sizeof(float), stream);
        scatter_add<<<sb, 256, 0, stream>>>(out, src, dst, hneigh, n_edges);
        linear_k<false><<<lb, 256, 0, stream>>>(hneigh, WT2, b2, out, n_nodes);
    }
}

// Round 4
// 365.565 us; speedup vs baseline: 8.0285x; 1.5185x over previous
//
#include <hip/hip_runtime.h>

// MPNN: h1 = relu(segsum(feat[src] -> dst) @ W1^T + b1)
//       out = segsum(h1[src] -> dst) @ W2^T + b2
// N=50000, E=800000, d=128, all f32.
//
// CSR by dst (int atomics) -> gather-side reduction (no f32 atomics)
// -> W-stationary LDS-tiled linear (operand reuse in LDS, not L2).

#define NDIM 128

// ---------------- weight transpose ----------------
__global__ void transpose_w2(const float* __restrict__ W1, const float* __restrict__ W2,
                             float* __restrict__ WT1, float* __restrict__ WT2) {
    int tid = blockIdx.x * 256 + threadIdx.x;   // 32768 threads
    int which = tid >> 14;
    int t = tid & 16383;
    int o = t >> 7;
    int i = t & 127;
    if (which == 0) WT1[i * NDIM + o] = W1[o * NDIM + i];
    else            WT2[i * NDIM + o] = W2[o * NDIM + i];
}

// ---------------- CSR build ----------------
__global__ void hist_dst(const int* __restrict__ dst, int* __restrict__ counts, int n_edges) {
    int i = blockIdx.x * blockDim.x + threadIdx.x;
    if (i < n_edges) atomicAdd(&counts[dst[i]], 1);
}

__global__ __launch_bounds__(1024) void scan_counts(const int* __restrict__ counts,
                                                    int* __restrict__ row_ptr,
                                                    int* __restrict__ cursor, int n) {
    __shared__ int part[1024];
    int t = threadIdx.x;
    int chunk = (n + 1023) / 1024;
    int beg = t * chunk;
    int end = min(beg + chunk, n);
    int s = 0;
    for (int i = beg; i < end; ++i) s += counts[i];
    part[t] = s;
    __syncthreads();
    for (int off = 1; off < 1024; off <<= 1) {
        int v = (t >= off) ? part[t - off] : 0;
        __syncthreads();
        part[t] += v;
        __syncthreads();
    }
    int run = (t == 0) ? 0 : part[t - 1];
    for (int i = beg; i < end; ++i) {
        row_ptr[i] = run;
        cursor[i]  = run;
        run += counts[i];
    }
    if (beg < n && end == n) row_ptr[n] = run;
    if (t == 1023 && beg >= n) row_ptr[n] = part[t - 1];
}

__global__ void fill_csr(const int* __restrict__ src, const int* __restrict__ dst,
                         int* __restrict__ cursor, int* __restrict__ col, int n_edges) {
    int i = blockIdx.x * blockDim.x + threadIdx.x;
    if (i < n_edges) {
        int pos = atomicAdd(&cursor[dst[i]], 1);
        col[pos] = src[i];
    }
}

// ---------------- gather-side segment sum ----------------
// One 64-lane wave per dst node. Lanes 0-31 take even edges, 32-63 odd edges;
// each lane accumulates a float4 (16B/lane = full 1KB per wave instruction).
// Unroll-2 keeps 2 gathers in flight per lane. __shfl combine in epilogue.
__global__ void aggregate(const float* __restrict__ feat,
                          const int* __restrict__ row_ptr,
                          const int* __restrict__ col,
                          float* __restrict__ out, int n_nodes) {
    int wid  = (blockIdx.x * blockDim.x + threadIdx.x) >> 6;
    int lane = threadIdx.x & 63;
    if (wid >= n_nodes) return;
    int half = lane >> 5;             // which edge-parity this lane handles
    int d4   = (lane & 31) << 2;      // feature dims d4..d4+3
    int beg = row_ptr[wid];
    int end = row_ptr[wid + 1];
    float ax = 0.f, ay = 0.f, az = 0.f, aw = 0.f;
    float bx = 0.f, by = 0.f, bz = 0.f, bw = 0.f;
    int k = beg + half;
    for (; k + 2 < end; k += 4) {
        int s0 = col[k];
        int s1 = col[k + 2];
        float4 v0 = *reinterpret_cast<const float4*>(feat + (size_t)s0 * NDIM + d4);
        float4 v1 = *reinterpret_cast<const float4*>(feat + (size_t)s1 * NDIM + d4);
        ax += v0.x; ay += v0.y; az += v0.z; aw += v0.w;
        bx += v1.x; by += v1.y; bz += v1.z; bw += v1.w;
    }
    if (k < end) {
        int s0 = col[k];
        float4 v0 = *reinterpret_cast<const float4*>(feat + (size_t)s0 * NDIM + d4);
        ax += v0.x; ay += v0.y; az += v0.z; aw += v0.w;
    }
    ax += bx; ay += by; az += bz; aw += bw;
    // combine the two halves (lane i <- lane i+32); both halves end up with total
    ax += __shfl(ax, lane ^ 32, 64);
    ay += __shfl(ay, lane ^ 32, 64);
    az += __shfl(az, lane ^ 32, 64);
    aw += __shfl(aw, lane ^ 32, 64);
    if (half == 0) {
        float4 r; r.x = ax; r.y = ay; r.z = az; r.w = aw;
        *reinterpret_cast<float4*>(out + (size_t)wid * NDIM + d4) = r;
    }
}

// ---------------- W-stationary LDS-tiled linear ----------------
// Block: 128 rows x 128 cols. 256 threads, each an 8x8 register tile.
// K chunked by 32: WT chunk [32][128] + transposed h tile [32][128(+4)] in LDS.
template <bool RELU>
__global__ __launch_bounds__(256) void linear_lds(const float* __restrict__ h,
                                                  const float* __restrict__ WT,
                                                  const float* __restrict__ bias,
                                                  float* __restrict__ out, int n_nodes) {
    __shared__ float wt_s[32 * 128];        // [k][c]
    __shared__ float ht_s[32 * 132];        // [k][r], stride 132 (pad 4)
    int t  = threadIdx.x;
    int ct = t & 15;          // 16 col-threads * 8 cols
    int rt = t >> 4;          // 16 row-threads * 8 rows
    int r0 = blockIdx.x * 128;

    float4 acc[8][2];
#pragma unroll
    for (int r = 0; r < 8; ++r) {
        acc[r][0] = make_float4(0.f, 0.f, 0.f, 0.f);
        acc[r][1] = make_float4(0.f, 0.f, 0.f, 0.f);
    }

    for (int kc = 0; kc < NDIM; kc += 32) {
        __syncthreads();
        // stage WT chunk: 4096 floats = 1024 float4, coalesced
        {
            const float4* wsrc = reinterpret_cast<const float4*>(WT + kc * NDIM);
            float4* wdst = reinterpret_cast<float4*>(wt_s);
#pragma unroll
            for (int i = 0; i < 4; ++i) wdst[t + 256 * i] = wsrc[t + 256 * i];
        }
        // stage h tile transposed: read h[r][kc+kk*4..+3] (float4), scatter to ht_s[k][r]
        // FULL chunk coverage: kk in 0..7 covers k-offsets 0..31 (round-3 bug: kk&3 covered only 0..15)
        {
            int rr = t >> 3;            // 0..31
            int kk = t & 7;             // 0..7 -> k offsets kk*4..kk*4+3
#pragma unroll
            for (int p = 0; p < 4; ++p) {
                int r = rr + p * 32;
                int gr = r0 + r;
                if (gr > n_nodes - 1) gr = n_nodes - 1;   // clamp (stores guarded later)
                float4 v = *reinterpret_cast<const float4*>(h + (size_t)gr * NDIM + kc + kk * 4);
                ht_s[(kk * 4 + 0) * 132 + r] = v.x;
                ht_s[(kk * 4 + 1) * 132 + r] = v.y;
                ht_s[(kk * 4 + 2) * 132 + r] = v.z;
                ht_s[(kk * 4 + 3) * 132 + r] = v.w;
            }
        }
        __syncthreads();

        const float4* wt4 = reinterpret_cast<const float4*>(wt_s);
        const float4* ht4 = reinterpret_cast<const float4*>(ht_s);
#pragma unroll
        for (int k = 0; k < 32; ++k) {
            float4 w0 = wt4[k * 32 + ct * 2];
            float4 w1 = wt4[k * 32 + ct * 2 + 1];
            float4 h0 = ht4[k * 33 + rt * 2];
            float4 h1 = ht4[k * 33 + rt * 2 + 1];
            float hs0[4] = {h0.x, h0.y, h0.z, h0.w};
            float hs1[4] = {h1.x, h1.y, h1.z, h1.w};
#pragma unroll
            for (int r = 0; r < 4; ++r) {
                float s = hs0[r];
                acc[r][0].x = fmaf(s, w0.x, acc[r][0].x);
                acc[r][0].y = fmaf(s, w0.y, acc[r][0].y);
                acc[r][0].z = fmaf(s, w0.z, acc[r][0].z);
                acc[r][0].w = fmaf(s, w0.w, acc[r][0].w);
                acc[r][1].x = fmaf(s, w1.x, acc[r][1].x);
                acc[r][1].y = fmaf(s, w1.y, acc[r][1].y);
                acc[r][1].z = fmaf(s, w1.z, acc[r][1].z);
                acc[r][1].w = fmaf(s, w1.w, acc[r][1].w);
            }
#pragma unroll
            for (int r = 0; r < 4; ++r) {
                float s = hs1[r];
                acc[r + 4][0].x = fmaf(s, w0.x, acc[r + 4][0].x);
                acc[r + 4][0].y = fmaf(s, w0.y, acc[r + 4][0].y);
                acc[r + 4][0].z = fmaf(s, w0.z, acc[r + 4][0].z);
                acc[r + 4][0].w = fmaf(s, w0.w, acc[r + 4][0].w);
                acc[r + 4][1].x = fmaf(s, w1.x, acc[r + 4][1].x);
                acc[r + 4][1].y = fmaf(s, w1.y, acc[r + 4][1].y);
                acc[r + 4][1].z = fmaf(s, w1.z, acc[r + 4][1].z);
                acc[r + 4][1].w = fmaf(s, w1.w, acc[r + 4][1].w);
            }
        }
    }

    int c8 = ct * 8;
    float4 bv0 = *reinterpret_cast<const float4*>(bias + c8);
    float4 bv1 = *reinterpret_cast<const float4*>(bias + c8 + 4);
#pragma unroll
    for (int r = 0; r < 8; ++r) {
        int gr = r0 + rt * 8 + r;
        if (gr >= n_nodes) continue;
        float4 o0 = acc[r][0], o1 = acc[r][1];
        o0.x += bv0.x; o0.y += bv0.y; o0.z += bv0.z; o0.w += bv0.w;
        o1.x += bv1.x; o1.y += bv1.y; o1.z += bv1.z; o1.w += bv1.w;
        if (RELU) {
            o0.x = fmaxf(o0.x, 0.f); o0.y = fmaxf(o0.y, 0.f);
            o0.z = fmaxf(o0.z, 0.f); o0.w = fmaxf(o0.w, 0.f);
            o1.x = fmaxf(o1.x, 0.f); o1.y = fmaxf(o1.y, 0.f);
            o1.z = fmaxf(o1.z, 0.f); o1.w = fmaxf(o1.w, 0.f);
        }
        float* op = out + (size_t)gr * NDIM + c8;
        *reinterpret_cast<float4*>(op)     = o0;
        *reinterpret_cast<float4*>(op + 4) = o1;
    }
}

extern "C" void kernel_launch(void* const* d_in, const int* in_sizes, int n_in,
                              void* d_out, int out_size, void* d_ws, size_t ws_size,
                              hipStream_t stream) {
    const float* features = (const float*)d_in[0];
    const int*   src      = (const int*)d_in[1];
    const int*   dst      = (const int*)d_in[2];
    const float* W1       = (const float*)d_in[3];
    const float* b1       = (const float*)d_in[4];
    const float* W2       = (const float*)d_in[5];
    const float* b2       = (const float*)d_in[6];
    float* out = (float*)d_out;

    int n_nodes = in_sizes[0] / NDIM;   // 50000
    int n_edges = in_sizes[1];          // 800000

    // ws layout
    float* hneigh = (float*)d_ws;                          // N*128 floats
    float* WT1    = hneigh + (size_t)n_nodes * NDIM;       // 16384
    float* WT2    = WT1 + NDIM * NDIM;                     // 16384
    int*   counts  = (int*)(WT2 + NDIM * NDIM);            // N
    int*   row_ptr = counts + n_nodes;                     // N+1
    int*   cursor  = row_ptr + n_nodes + 1;                // N
    int*   col     = cursor + n_nodes;                     // E

    transpose_w2<<<128, 256, 0, stream>>>(W1, W2, WT1, WT2);

    // ---- CSR build (reused by both layers) ----
    hipMemsetAsync(counts, 0, (size_t)n_nodes * sizeof(int), stream);
    int eb = (n_edges + 255) / 256;
    hist_dst<<<eb, 256, 0, stream>>>(dst, counts, n_edges);
    scan_counts<<<1, 1024, 0, stream>>>(counts, row_ptr, cursor, n_nodes);
    fill_csr<<<eb, 256, 0, stream>>>(src, dst, cursor, col, n_edges);

    int ab = (int)(((long)n_nodes * 64 + 255) / 256);   // one wave per node
    int lb = (n_nodes + 127) / 128;                     // 128 rows per block

    // ---- Layer 1 ----
    aggregate<<<ab, 256, 0, stream>>>(features, row_ptr, col, hneigh, n_nodes);
    linear_lds<true><<<lb, 256, 0, stream>>>(hneigh, WT1, b1, out, n_nodes);
    // ---- Layer 2 ---- (h1 lives in d_out)
    aggregate<<<ab, 256, 0, stream>>>(out, row_ptr, col, hneigh, n_nodes);
    linear_lds<false><<<lb, 256, 0, stream>>>(hneigh, WT2, b2, out, n_nodes);
}

// Round 5
// 265.378 us; speedup vs baseline: 11.0595x; 1.3775x over previous
//
#include <hip/hip_runtime.h>

// MPNN: h1 = relu(segsum(feat[src] -> dst) @ W1^T + b1)
//       out = segsum(h1[src] -> dst) @ W2^T + b2
// N=50000, E=800000, d=128, all f32.
//
// CSR by dst (int atomics) -> gather-side reduction (no f32 atomics)
// -> W-stationary LDS-tiled linear. Round 4->5: single-block scan (111us,
// 0.14% occupancy) replaced by 3-kernel hierarchical scan (~12us).

#define NDIM 128
#define SCAN_BS 512

// ---------------- weight transpose ----------------
__global__ void transpose_w2(const float* __restrict__ W1, const float* __restrict__ W2,
                             float* __restrict__ WT1, float* __restrict__ WT2) {
    int tid = blockIdx.x * 256 + threadIdx.x;   // 32768 threads
    int which = tid >> 14;
    int t = tid & 16383;
    int o = t >> 7;
    int i = t & 127;
    if (which == 0) WT1[i * NDIM + o] = W1[o * NDIM + i];
    else            WT2[i * NDIM + o] = W2[o * NDIM + i];
}

// ---------------- CSR build ----------------
__global__ void hist_dst(const int* __restrict__ dst, int* __restrict__ counts, int n_edges) {
    int i = blockIdx.x * blockDim.x + threadIdx.x;
    if (i < n_edges) atomicAdd(&counts[dst[i]], 1);
}

// Phase A: per-block local exclusive scan + block sum. Coalesced.
__global__ __launch_bounds__(SCAN_BS) void scan_local(const int* __restrict__ counts,
                                                      int* __restrict__ row_ptr,
                                                      int* __restrict__ block_sums, int n) {
    __shared__ int sh[SCAN_BS];
    int t = threadIdx.x;
    int i = blockIdx.x * SCAN_BS + t;
    int v = (i < n) ? counts[i] : 0;
    sh[t] = v;
    __syncthreads();
    for (int off = 1; off < SCAN_BS; off <<= 1) {
        int u = (t >= off) ? sh[t - off] : 0;
        __syncthreads();
        sh[t] += u;
        __syncthreads();
    }
    if (i < n) row_ptr[i] = sh[t] - v;                 // local exclusive prefix
    if (t == SCAN_BS - 1) block_sums[blockIdx.x] = sh[t];
}

// Phase B: inclusive scan of block sums (nb <= 128), one block.
__global__ __launch_bounds__(128) void scan_blocksums(int* __restrict__ block_sums, int nb) {
    __shared__ int sh[128];
    int t = threadIdx.x;
    sh[t] = (t < nb) ? block_sums[t] : 0;
    __syncthreads();
    for (int off = 1; off < 128; off <<= 1) {
        int u = (t >= off) ? sh[t - off] : 0;
        __syncthreads();
        sh[t] += u;
        __syncthreads();
    }
    if (t < nb) block_sums[t] = sh[t];                 // inclusive
}

// Phase C: add block offset, emit row_ptr + cursor, set row_ptr[n].
__global__ __launch_bounds__(SCAN_BS) void scan_apply(int* __restrict__ row_ptr,
                                                      int* __restrict__ cursor,
                                                      const int* __restrict__ block_sums,
                                                      int n, int nb) {
    int b = blockIdx.x;
    int i = b * SCAN_BS + threadIdx.x;
    int add = (b == 0) ? 0 : block_sums[b - 1];
    if (i < n) {
        int r = row_ptr[i] + add;
        row_ptr[i] = r;
        cursor[i]  = r;
    }
    if (i == 0) row_ptr[n] = block_sums[nb - 1];
}

__global__ void fill_csr(const int* __restrict__ src, const int* __restrict__ dst,
                         int* __restrict__ cursor, int* __restrict__ col, int n_edges) {
    int i = blockIdx.x * blockDim.x + threadIdx.x;
    if (i < n_edges) {
        int pos = atomicAdd(&cursor[dst[i]], 1);
        col[pos] = src[i];
    }
}

// ---------------- gather-side segment sum ----------------
// One 64-lane wave per dst node. Lanes 0-31 take even edges, 32-63 odd edges;
// each lane accumulates a float4. Unroll-2 keeps 2 gathers in flight per lane.
__global__ void aggregate(const float* __restrict__ feat,
                          const int* __restrict__ row_ptr,
                          const int* __restrict__ col,
                          float* __restrict__ out, int n_nodes) {
    int wid  = (blockIdx.x * blockDim.x + threadIdx.x) >> 6;
    int lane = threadIdx.x & 63;
    if (wid >= n_nodes) return;
    int half = lane >> 5;
    int d4   = (lane & 31) << 2;
    int beg = row_ptr[wid];
    int end = row_ptr[wid + 1];
    float ax = 0.f, ay = 0.f, az = 0.f, aw = 0.f;
    float bx = 0.f, by = 0.f, bz = 0.f, bw = 0.f;
    int k = beg + half;
    for (; k + 2 < end; k += 4) {
        int s0 = col[k];
        int s1 = col[k + 2];
        float4 v0 = *reinterpret_cast<const float4*>(feat + (size_t)s0 * NDIM + d4);
        float4 v1 = *reinterpret_cast<const float4*>(feat + (size_t)s1 * NDIM + d4);
        ax += v0.x; ay += v0.y; az += v0.z; aw += v0.w;
        bx += v1.x; by += v1.y; bz += v1.z; bw += v1.w;
    }
    if (k < end) {
        int s0 = col[k];
        float4 v0 = *reinterpret_cast<const float4*>(feat + (size_t)s0 * NDIM + d4);
        ax += v0.x; ay += v0.y; az += v0.z; aw += v0.w;
    }
    ax += bx; ay += by; az += bz; aw += bw;
    ax += __shfl(ax, lane ^ 32, 64);
    ay += __shfl(ay, lane ^ 32, 64);
    az += __shfl(az, lane ^ 32, 64);
    aw += __shfl(aw, lane ^ 32, 64);
    if (half == 0) {
        float4 r; r.x = ax; r.y = ay; r.z = az; r.w = aw;
        *reinterpret_cast<float4*>(out + (size_t)wid * NDIM + d4) = r;
    }
}

// ---------------- W-stationary LDS-tiled linear ----------------
template <bool RELU>
__global__ __launch_bounds__(256) void linear_lds(const float* __restrict__ h,
                                                  const float* __restrict__ WT,
                                                  const float* __restrict__ bias,
                                                  float* __restrict__ out, int n_nodes) {
    __shared__ float wt_s[32 * 128];        // [k][c]
    __shared__ float ht_s[32 * 132];        // [k][r], stride 132 (pad 4)
    int t  = threadIdx.x;
    int ct = t & 15;
    int rt = t >> 4;
    int r0 = blockIdx.x * 128;

    float4 acc[8][2];
#pragma unroll
    for (int r = 0; r < 8; ++r) {
        acc[r][0] = make_float4(0.f, 0.f, 0.f, 0.f);
        acc[r][1] = make_float4(0.f, 0.f, 0.f, 0.f);
    }

    for (int kc = 0; kc < NDIM; kc += 32) {
        __syncthreads();
        {
            const float4* wsrc = reinterpret_cast<const float4*>(WT + kc * NDIM);
            float4* wdst = reinterpret_cast<float4*>(wt_s);
#pragma unroll
            for (int i = 0; i < 4; ++i) wdst[t + 256 * i] = wsrc[t + 256 * i];
        }
        {
            int rr = t >> 3;            // 0..31
            int kk = t & 7;             // 0..7 -> k offsets kk*4..kk*4+3
#pragma unroll
            for (int p = 0; p < 4; ++p) {
                int r = rr + p * 32;
                int gr = r0 + r;
                if (gr > n_nodes - 1) gr = n_nodes - 1;
                float4 v = *reinterpret_cast<const float4*>(h + (size_t)gr * NDIM + kc + kk * 4);
                ht_s[(kk * 4 + 0) * 132 + r] = v.x;
                ht_s[(kk * 4 + 1) * 132 + r] = v.y;
                ht_s[(kk * 4 + 2) * 132 + r] = v.z;
                ht_s[(kk * 4 + 3) * 132 + r] = v.w;
            }
        }
        __syncthreads();

        const float4* wt4 = reinterpret_cast<const float4*>(wt_s);
        const float4* ht4 = reinterpret_cast<const float4*>(ht_s);
#pragma unroll
        for (int k = 0; k < 32; ++k) {
            float4 w0 = wt4[k * 32 + ct * 2];
            float4 w1 = wt4[k * 32 + ct * 2 + 1];
            float4 h0 = ht4[k * 33 + rt * 2];
            float4 h1 = ht4[k * 33 + rt * 2 + 1];
            float hs0[4] = {h0.x, h0.y, h0.z, h0.w};
            float hs1[4] = {h1.x, h1.y, h1.z, h1.w};
#pragma unroll
            for (int r = 0; r < 4; ++r) {
                float s = hs0[r];
                acc[r][0].x = fmaf(s, w0.x, acc[r][0].x);
                acc[r][0].y = fmaf(s, w0.y, acc[r][0].y);
                acc[r][0].z = fmaf(s, w0.z, acc[r][0].z);
                acc[r][0].w = fmaf(s, w0.w, acc[r][0].w);
                acc[r][1].x = fmaf(s, w1.x, acc[r][1].x);
                acc[r][1].y = fmaf(s, w1.y, acc[r][1].y);
                acc[r][1].z = fmaf(s, w1.z, acc[r][1].z);
                acc[r][1].w = fmaf(s, w1.w, acc[r][1].w);
            }
#pragma unroll
            for (int r = 0; r < 4; ++r) {
                float s = hs1[r];
                acc[r + 4][0].x = fmaf(s, w0.x, acc[r + 4][0].x);
                acc[r + 4][0].y = fmaf(s, w0.y, acc[r + 4][0].y);
                acc[r + 4][0].z = fmaf(s, w0.z, acc[r + 4][0].z);
                acc[r + 4][0].w = fmaf(s, w0.w, acc[r + 4][0].w);
                acc[r + 4][1].x = fmaf(s, w1.x, acc[r + 4][1].x);
                acc[r + 4][1].y = fmaf(s, w1.y, acc[r + 4][1].y);
                acc[r + 4][1].z = fmaf(s, w1.z, acc[r + 4][1].z);
                acc[r + 4][1].w = fmaf(s, w1.w, acc[r + 4][1].w);
            }
        }
    }

    int c8 = ct * 8;
    float4 bv0 = *reinterpret_cast<const float4*>(bias + c8);
    float4 bv1 = *reinterpret_cast<const float4*>(bias + c8 + 4);
#pragma unroll
    for (int r = 0; r < 8; ++r) {
        int gr = r0 + rt * 8 + r;
        if (gr >= n_nodes) continue;
        float4 o0 = acc[r][0], o1 = acc[r][1];
        o0.x += bv0.x; o0.y += bv0.y; o0.z += bv0.z; o0.w += bv0.w;
        o1.x += bv1.x; o1.y += bv1.y; o1.z += bv1.z; o1.w += bv1.w;
        if (RELU) {
            o0.x = fmaxf(o0.x, 0.f); o0.y = fmaxf(o0.y, 0.f);
            o0.z = fmaxf(o0.z, 0.f); o0.w = fmaxf(o0.w, 0.f);
            o1.x = fmaxf(o1.x, 0.f); o1.y = fmaxf(o1.y, 0.f);
            o1.z = fmaxf(o1.z, 0.f); o1.w = fmaxf(o1.w, 0.f);
        }
        float* op = out + (size_t)gr * NDIM + c8;
        *reinterpret_cast<float4*>(op)     = o0;
        *reinterpret_cast<float4*>(op + 4) = o1;
    }
}

extern "C" void kernel_launch(void* const* d_in, const int* in_sizes, int n_in,
                              void* d_out, int out_size, void* d_ws, size_t ws_size,
                              hipStream_t stream) {
    const float* features = (const float*)d_in[0];
    const int*   src      = (const int*)d_in[1];
    const int*   dst      = (const int*)d_in[2];
    const float* W1       = (const float*)d_in[3];
    const float* b1       = (const float*)d_in[4];
    const float* W2       = (const float*)d_in[5];
    const float* b2       = (const float*)d_in[6];
    float* out = (float*)d_out;

    int n_nodes = in_sizes[0] / NDIM;   // 50000
    int n_edges = in_sizes[1];          // 800000

    // ws layout
    float* hneigh = (float*)d_ws;                          // N*128 floats
    float* WT1    = hneigh + (size_t)n_nodes * NDIM;       // 16384
    float* WT2    = WT1 + NDIM * NDIM;                     // 16384
    int*   counts     = (int*)(WT2 + NDIM * NDIM);         // N
    int*   row_ptr    = counts + n_nodes;                  // N+1
    int*   cursor     = row_ptr + n_nodes + 1;             // N
    int*   block_sums = cursor + n_nodes;                  // 128
    int*   col        = block_sums + 128;                  // E

    transpose_w2<<<128, 256, 0, stream>>>(W1, W2, WT1, WT2);

    // ---- CSR build (reused by both layers) ----
    hipMemsetAsync(counts, 0, (size_t)n_nodes * sizeof(int), stream);
    int eb = (n_edges + 255) / 256;
    hist_dst<<<eb, 256, 0, stream>>>(dst, counts, n_edges);
    int nb = (n_nodes + SCAN_BS - 1) / SCAN_BS;            // 98
    scan_local<<<nb, SCAN_BS, 0, stream>>>(counts, row_ptr, block_sums, n_nodes);
    scan_blocksums<<<1, 128, 0, stream>>>(block_sums, nb);
    scan_apply<<<nb, SCAN_BS, 0, stream>>>(row_ptr, cursor, block_sums, n_nodes, nb);
    fill_csr<<<eb, 256, 0, stream>>>(src, dst, cursor, col, n_edges);

    int ab = (int)(((long)n_nodes * 64 + 255) / 256);   // one wave per node
    int lb = (n_nodes + 127) / 128;                     // 128 rows per block

    // ---- Layer 1 ----
    aggregate<<<ab, 256, 0, stream>>>(features, row_ptr, col, hneigh, n_nodes);
    linear_lds<true><<<lb, 256, 0, stream>>>(hneigh, WT1, b1, out, n_nodes);
    // ---- Layer 2 ---- (h1 lives in d_out)
    aggregate<<<ab, 256, 0, stream>>>(out, row_ptr, col, hneigh, n_nodes);
    linear_lds<false><<<lb, 256, 0, stream>>>(hneigh, WT2, b2, out, n_nodes);
}

// Round 6
// 235.896 us; speedup vs baseline: 12.4417x; 1.1250x over previous
//
#include <hip/hip_runtime.h>

// MPNN: h1 = relu(segsum(feat[src] -> dst) @ W1^T + b1)
//       out = segsum(h1[src] -> dst) @ W2^T + b2
// N=50000, E=800000, d=128.
//
// CSR by dst -> gather-side reduction. Round 5->6: gathered tables stored as
// bf16 (RNE) -> half the gather bytes; 4 edges per wave-load (16 lanes/edge,
// 16B/lane); f32 accumulation; W/bias stay f32. h1 passes between layers as
// bf16 stashed in d_out's storage. Fallback to f32 path if ws too small.

#define NDIM 128
#define SCAN_BS 512

__device__ inline unsigned short f2bf_rne(float x) {
    unsigned u = __float_as_uint(x);
    unsigned lsb = (u >> 16) & 1u;
    u += 0x7fffu + lsb;
    return (unsigned short)(u >> 16);
}

// ---------------- weight transpose ----------------
__global__ void transpose_w2(const float* __restrict__ W1, const float* __restrict__ W2,
                             float* __restrict__ WT1, float* __restrict__ WT2) {
    int tid = blockIdx.x * 256 + threadIdx.x;   // 32768 threads
    int which = tid >> 14;
    int t = tid & 16383;
    int o = t >> 7;
    int i = t & 127;
    if (which == 0) WT1[i * NDIM + o] = W1[o * NDIM + i];
    else            WT2[i * NDIM + o] = W2[o * NDIM + i];
}

// ---------------- f32 -> bf16 table conversion ----------------
// one thread per 8 floats (32B read, 16B write)
__global__ void convert_bf(const float* __restrict__ in, unsigned short* __restrict__ out,
                           int n8) {
    int i = blockIdx.x * blockDim.x + threadIdx.x;
    if (i >= n8) return;
    const float4* p = reinterpret_cast<const float4*>(in + (size_t)i * 8);
    float4 a = p[0], b = p[1];
    uint4 pk;
    pk.x = (unsigned)f2bf_rne(a.x) | ((unsigned)f2bf_rne(a.y) << 16);
    pk.y = (unsigned)f2bf_rne(a.z) | ((unsigned)f2bf_rne(a.w) << 16);
    pk.z = (unsigned)f2bf_rne(b.x) | ((unsigned)f2bf_rne(b.y) << 16);
    pk.w = (unsigned)f2bf_rne(b.z) | ((unsigned)f2bf_rne(b.w) << 16);
    *reinterpret_cast<uint4*>(out + (size_t)i * 8) = pk;
}

// ---------------- CSR build ----------------
__global__ void hist_dst(const int* __restrict__ dst, int* __restrict__ counts, int n_edges) {
    int i = blockIdx.x * blockDim.x + threadIdx.x;
    if (i < n_edges) atomicAdd(&counts[dst[i]], 1);
}

__global__ __launch_bounds__(SCAN_BS) void scan_local(const int* __restrict__ counts,
                                                      int* __restrict__ row_ptr,
                                                      int* __restrict__ block_sums, int n) {
    __shared__ int sh[SCAN_BS];
    int t = threadIdx.x;
    int i = blockIdx.x * SCAN_BS + t;
    int v = (i < n) ? counts[i] : 0;
    sh[t] = v;
    __syncthreads();
    for (int off = 1; off < SCAN_BS; off <<= 1) {
        int u = (t >= off) ? sh[t - off] : 0;
        __syncthreads();
        sh[t] += u;
        __syncthreads();
    }
    if (i < n) row_ptr[i] = sh[t] - v;
    if (t == SCAN_BS - 1) block_sums[blockIdx.x] = sh[t];
}

__global__ __launch_bounds__(128) void scan_blocksums(int* __restrict__ block_sums, int nb) {
    __shared__ int sh[128];
    int t = threadIdx.x;
    sh[t] = (t < nb) ? block_sums[t] : 0;
    __syncthreads();
    for (int off = 1; off < 128; off <<= 1) {
        int u = (t >= off) ? sh[t - off] : 0;
        __syncthreads();
        sh[t] += u;
        __syncthreads();
    }
    if (t < nb) block_sums[t] = sh[t];
}

__global__ __launch_bounds__(SCAN_BS) void scan_apply(int* __restrict__ row_ptr,
                                                      int* __restrict__ cursor,
                                                      const int* __restrict__ block_sums,
                                                      int n, int nb) {
    int b = blockIdx.x;
    int i = b * SCAN_BS + threadIdx.x;
    int add = (b == 0) ? 0 : block_sums[b - 1];
    if (i < n) {
        int r = row_ptr[i] + add;
        row_ptr[i] = r;
        cursor[i]  = r;
    }
    if (i == 0) row_ptr[n] = block_sums[nb - 1];
}

__global__ void fill_csr(const int* __restrict__ src, const int* __restrict__ dst,
                         int* __restrict__ cursor, int* __restrict__ col, int n_edges) {
    int i = blockIdx.x * blockDim.x + threadIdx.x;
    if (i < n_edges) {
        int pos = atomicAdd(&cursor[dst[i]], 1);
        col[pos] = src[i];
    }
}

// ---------------- bf16 gather-side segment sum ----------------
// One wave per dst node. 16 lanes per edge (4 edges per wave-instr); each lane
// loads bf16x8 (16B) of the row. f32 accumulate; xor-shfl combine; lanes 0-15
// write the f32 result row.
__global__ void aggregate_bf(const uint4* __restrict__ feat_bf,   // [N][16] uint4
                             const int* __restrict__ row_ptr,
                             const int* __restrict__ col,
                             float* __restrict__ out, int n_nodes) {
    int wid  = (blockIdx.x * blockDim.x + threadIdx.x) >> 6;
    int lane = threadIdx.x & 63;
    if (wid >= n_nodes) return;
    int sub = lane >> 4;            // edge slot 0..3
    int d   = lane & 15;            // 16B chunk within row
    int beg = row_ptr[wid];
    int end = row_ptr[wid + 1];
    float acc[8] = {0.f,0.f,0.f,0.f,0.f,0.f,0.f,0.f};

    int e = beg + sub;
    // 2 quads in flight
    for (; e + 4 < end; e += 8) {
        int s0 = col[e];
        int s1 = col[e + 4];
        uint4 a = feat_bf[(size_t)s0 * 16 + d];
        uint4 b = feat_bf[(size_t)s1 * 16 + d];
        unsigned aw[4] = {a.x, a.y, a.z, a.w};
        unsigned bw[4] = {b.x, b.y, b.z, b.w};
#pragma unroll
        for (int j = 0; j < 4; ++j) {
            acc[2*j]   += __uint_as_float(aw[j] << 16);
            acc[2*j+1] += __uint_as_float(aw[j] & 0xFFFF0000u);
            acc[2*j]   += __uint_as_float(bw[j] << 16);
            acc[2*j+1] += __uint_as_float(bw[j] & 0xFFFF0000u);
        }
    }
    for (; e < end; e += 4) {
        int s0 = col[e];
        uint4 a = feat_bf[(size_t)s0 * 16 + d];
        unsigned aw[4] = {a.x, a.y, a.z, a.w};
#pragma unroll
        for (int j = 0; j < 4; ++j) {
            acc[2*j]   += __uint_as_float(aw[j] << 16);
            acc[2*j+1] += __uint_as_float(aw[j] & 0xFFFF0000u);
        }
    }
    // combine 4 edge slots
#pragma unroll
    for (int j = 0; j < 8; ++j) {
        acc[j] += __shfl_xor(acc[j], 16, 64);
        acc[j] += __shfl_xor(acc[j], 32, 64);
    }
    if (sub == 0) {
        float4 r0 = make_float4(acc[0], acc[1], acc[2], acc[3]);
        float4 r1 = make_float4(acc[4], acc[5], acc[6], acc[7]);
        float* op = out + (size_t)wid * NDIM + d * 8;
        *reinterpret_cast<float4*>(op)     = r0;
        *reinterpret_cast<float4*>(op + 4) = r1;
    }
}

// ---------------- f32 gather (fallback path) ----------------
__global__ void aggregate(const float* __restrict__ feat,
                          const int* __restrict__ row_ptr,
                          const int* __restrict__ col,
                          float* __restrict__ out, int n_nodes) {
    int wid  = (blockIdx.x * blockDim.x + threadIdx.x) >> 6;
    int lane = threadIdx.x & 63;
    if (wid >= n_nodes) return;
    int half = lane >> 5;
    int d4   = (lane & 31) << 2;
    int beg = row_ptr[wid];
    int end = row_ptr[wid + 1];
    float ax = 0.f, ay = 0.f, az = 0.f, aw = 0.f;
    float bx = 0.f, by = 0.f, bz = 0.f, bw = 0.f;
    int k = beg + half;
    for (; k + 2 < end; k += 4) {
        int s0 = col[k];
        int s1 = col[k + 2];
        float4 v0 = *reinterpret_cast<const float4*>(feat + (size_t)s0 * NDIM + d4);
        float4 v1 = *reinterpret_cast<const float4*>(feat + (size_t)s1 * NDIM + d4);
        ax += v0.x; ay += v0.y; az += v0.z; aw += v0.w;
        bx += v1.x; by += v1.y; bz += v1.z; bw += v1.w;
    }
    if (k < end) {
        int s0 = col[k];
        float4 v0 = *reinterpret_cast<const float4*>(feat + (size_t)s0 * NDIM + d4);
        ax += v0.x; ay += v0.y; az += v0.z; aw += v0.w;
    }
    ax += bx; ay += by; az += bz; aw += bw;
    ax += __shfl(ax, lane ^ 32, 64);
    ay += __shfl(ay, lane ^ 32, 64);
    az += __shfl(az, lane ^ 32, 64);
    aw += __shfl(aw, lane ^ 32, 64);
    if (half == 0) {
        float4 r; r.x = ax; r.y = ay; r.z = az; r.w = aw;
        *reinterpret_cast<float4*>(out + (size_t)wid * NDIM + d4) = r;
    }
}

// ---------------- W-stationary LDS-tiled linear ----------------
// OUTBF: write bf16 (packed) instead of f32.
template <bool RELU, bool OUTBF>
__global__ __launch_bounds__(256) void linear_lds(const float* __restrict__ h,
                                                  const float* __restrict__ WT,
                                                  const float* __restrict__ bias,
                                                  float* __restrict__ out,
                                                  unsigned short* __restrict__ out_bf,
                                                  int n_nodes) {
    __shared__ float wt_s[32 * 128];        // [k][c]
    __shared__ float ht_s[32 * 132];        // [k][r], stride 132
    int t  = threadIdx.x;
    int ct = t & 15;
    int rt = t >> 4;
    int r0 = blockIdx.x * 128;

    float4 acc[8][2];
#pragma unroll
    for (int r = 0; r < 8; ++r) {
        acc[r][0] = make_float4(0.f, 0.f, 0.f, 0.f);
        acc[r][1] = make_float4(0.f, 0.f, 0.f, 0.f);
    }

    for (int kc = 0; kc < NDIM; kc += 32) {
        __syncthreads();
        {
            const float4* wsrc = reinterpret_cast<const float4*>(WT + kc * NDIM);
            float4* wdst = reinterpret_cast<float4*>(wt_s);
#pragma unroll
            for (int i = 0; i < 4; ++i) wdst[t + 256 * i] = wsrc[t + 256 * i];
        }
        {
            int rr = t >> 3;            // 0..31
            int kk = t & 7;             // 0..7
#pragma unroll
            for (int p = 0; p < 4; ++p) {
                int r = rr + p * 32;
                int gr = r0 + r;
                if (gr > n_nodes - 1) gr = n_nodes - 1;
                float4 v = *reinterpret_cast<const float4*>(h + (size_t)gr * NDIM + kc + kk * 4);
                ht_s[(kk * 4 + 0) * 132 + r] = v.x;
                ht_s[(kk * 4 + 1) * 132 + r] = v.y;
                ht_s[(kk * 4 + 2) * 132 + r] = v.z;
                ht_s[(kk * 4 + 3) * 132 + r] = v.w;
            }
        }
        __syncthreads();

        const float4* wt4 = reinterpret_cast<const float4*>(wt_s);
        const float4* ht4 = reinterpret_cast<const float4*>(ht_s);
#pragma unroll
        for (int k = 0; k < 32; ++k) {
            float4 w0 = wt4[k * 32 + ct * 2];
            float4 w1 = wt4[k * 32 + ct * 2 + 1];
            float4 h0 = ht4[k * 33 + rt * 2];
            float4 h1 = ht4[k * 33 + rt * 2 + 1];
            float hs0[4] = {h0.x, h0.y, h0.z, h0.w};
            float hs1[4] = {h1.x, h1.y, h1.z, h1.w};
#pragma unroll
            for (int r = 0; r < 4; ++r) {
                float s = hs0[r];
                acc[r][0].x = fmaf(s, w0.x, acc[r][0].x);
                acc[r][0].y = fmaf(s, w0.y, acc[r][0].y);
                acc[r][0].z = fmaf(s, w0.z, acc[r][0].z);
                acc[r][0].w = fmaf(s, w0.w, acc[r][0].w);
                acc[r][1].x = fmaf(s, w1.x, acc[r][1].x);
                acc[r][1].y = fmaf(s, w1.y, acc[r][1].y);
                acc[r][1].z = fmaf(s, w1.z, acc[r][1].z);
                acc[r][1].w = fmaf(s, w1.w, acc[r][1].w);
            }
#pragma unroll
            for (int r = 0; r < 4; ++r) {
                float s = hs1[r];
                acc[r + 4][0].x = fmaf(s, w0.x, acc[r + 4][0].x);
                acc[r + 4][0].y = fmaf(s, w0.y, acc[r + 4][0].y);
                acc[r + 4][0].z = fmaf(s, w0.z, acc[r + 4][0].z);
                acc[r + 4][0].w = fmaf(s, w0.w, acc[r + 4][0].w);
                acc[r + 4][1].x = fmaf(s, w1.x, acc[r + 4][1].x);
                acc[r + 4][1].y = fmaf(s, w1.y, acc[r + 4][1].y);
                acc[r + 4][1].z = fmaf(s, w1.z, acc[r + 4][1].z);
                acc[r + 4][1].w = fmaf(s, w1.w, acc[r + 4][1].w);
            }
        }
    }

    int c8 = ct * 8;
    float4 bv0 = *reinterpret_cast<const float4*>(bias + c8);
    float4 bv1 = *reinterpret_cast<const float4*>(bias + c8 + 4);
#pragma unroll
    for (int r = 0; r < 8; ++r) {
        int gr = r0 + rt * 8 + r;
        if (gr >= n_nodes) continue;
        float4 o0 = acc[r][0], o1 = acc[r][1];
        o0.x += bv0.x; o0.y += bv0.y; o0.z += bv0.z; o0.w += bv0.w;
        o1.x += bv1.x; o1.y += bv1.y; o1.z += bv1.z; o1.w += bv1.w;
        if (RELU) {
            o0.x = fmaxf(o0.x, 0.f); o0.y = fmaxf(o0.y, 0.f);
            o0.z = fmaxf(o0.z, 0.f); o0.w = fmaxf(o0.w, 0.f);
            o1.x = fmaxf(o1.x, 0.f); o1.y = fmaxf(o1.y, 0.f);
            o1.z = fmaxf(o1.z, 0.f); o1.w = fmaxf(o1.w, 0.f);
        }
        if (OUTBF) {
            uint4 pk;
            pk.x = (unsigned)f2bf_rne(o0.x) | ((unsigned)f2bf_rne(o0.y) << 16);
            pk.y = (unsigned)f2bf_rne(o0.z) | ((unsigned)f2bf_rne(o0.w) << 16);
            pk.z = (unsigned)f2bf_rne(o1.x) | ((unsigned)f2bf_rne(o1.y) << 16);
            pk.w = (unsigned)f2bf_rne(o1.z) | ((unsigned)f2bf_rne(o1.w) << 16);
            *reinterpret_cast<uint4*>(out_bf + (size_t)gr * NDIM + c8) = pk;
        } else {
            float* op = out + (size_t)gr * NDIM + c8;
            *reinterpret_cast<float4*>(op)     = o0;
            *reinterpret_cast<float4*>(op + 4) = o1;
        }
    }
}

extern "C" void kernel_launch(void* const* d_in, const int* in_sizes, int n_in,
                              void* d_out, int out_size, void* d_ws, size_t ws_size,
                              hipStream_t stream) {
    const float* features = (const float*)d_in[0];
    const int*   src      = (const int*)d_in[1];
    const int*   dst      = (const int*)d_in[2];
    const float* W1       = (const float*)d_in[3];
    const float* b1       = (const float*)d_in[4];
    const float* W2       = (const float*)d_in[5];
    const float* b2       = (const float*)d_in[6];
    float* out = (float*)d_out;

    int n_nodes = in_sizes[0] / NDIM;   // 50000
    int n_edges = in_sizes[1];          // 800000

    // ws layout
    float* hneigh = (float*)d_ws;                          // N*128 f32
    float* WT1    = hneigh + (size_t)n_nodes * NDIM;       // 16384
    float* WT2    = WT1 + NDIM * NDIM;                     // 16384
    int*   counts     = (int*)(WT2 + NDIM * NDIM);         // N
    int*   row_ptr    = counts + n_nodes;                  // N+1
    int*   cursor     = row_ptr + n_nodes + 1;             // N
    int*   block_sums = cursor + n_nodes;                  // 128
    int*   col        = block_sums + 128;                  // E
    unsigned short* feat_bf = (unsigned short*)(col + n_edges);   // N*128 bf16
    size_t needed = ((size_t)n_nodes * NDIM + 2 * NDIM * NDIM) * sizeof(float)
                  + ((size_t)3 * n_nodes + 1 + 128 + n_edges) * sizeof(int)
                  + (size_t)n_nodes * NDIM * sizeof(unsigned short);
    // h1 in bf16 lives in d_out's storage (fully overwritten by linear2 later)
    unsigned short* h1_bf = (unsigned short*)d_out;

    transpose_w2<<<128, 256, 0, stream>>>(W1, W2, WT1, WT2);

    // ---- CSR build (reused by both layers) ----
    hipMemsetAsync(counts, 0, (size_t)n_nodes * sizeof(int), stream);
    int eb = (n_edges + 255) / 256;
    hist_dst<<<eb, 256, 0, stream>>>(dst, counts, n_edges);
    int nb = (n_nodes + SCAN_BS - 1) / SCAN_BS;            // 98
    scan_local<<<nb, SCAN_BS, 0, stream>>>(counts, row_ptr, block_sums, n_nodes);
    scan_blocksums<<<1, 128, 0, stream>>>(block_sums, nb);
    scan_apply<<<nb, SCAN_BS, 0, stream>>>(row_ptr, cursor, block_sums, n_nodes, nb);
    fill_csr<<<eb, 256, 0, stream>>>(src, dst, cursor, col, n_edges);

    int ab = (int)(((long)n_nodes * 64 + 255) / 256);   // one wave per node
    int lb = (n_nodes + 127) / 128;                     // 128 rows per block

    if (ws_size >= needed) {
        // ---- bf16 gather path ----
        int n8 = n_nodes * (NDIM / 8);
        convert_bf<<<(n8 + 255) / 256, 256, 0, stream>>>(features, feat_bf, n8);

        // Layer 1
        aggregate_bf<<<ab, 256, 0, stream>>>((const uint4*)feat_bf, row_ptr, col, hneigh, n_nodes);
        linear_lds<true, true><<<lb, 256, 0, stream>>>(hneigh, WT1, b1, nullptr, h1_bf, n_nodes);
        // Layer 2 (gather h1_bf from d_out storage, then overwrite d_out)
        aggregate_bf<<<ab, 256, 0, stream>>>((const uint4*)h1_bf, row_ptr, col, hneigh, n_nodes);
        linear_lds<false, false><<<lb, 256, 0, stream>>>(hneigh, WT2, b2, out, nullptr, n_nodes);
    } else {
        // ---- f32 fallback (round-5 path) ----
        aggregate<<<ab, 256, 0, stream>>>(features, row_ptr, col, hneigh, n_nodes);
        linear_lds<true, false><<<lb, 256, 0, stream>>>(hneigh, WT1, b1, out, nullptr, n_nodes);
        aggregate<<<ab, 256, 0, stream>>>(out, row_ptr, col, hneigh, n_nodes);
        linear_lds<false, false><<<lb, 256, 0, stream>>>(hneigh, WT2, b2, out, nullptr, n_nodes);
    }
}